// Round 3
// baseline (139.990 us; speedup 1.0000x reference)
//
#include <hip/hip_runtime.h>

// BoxDetectionLoss on MI355X — single fused kernel.
//   Blocks 0..NB-1 : partial sums of sigmoid(conf)^2 over the 3 conf channels
//                    per batch (25.2 MB of the 75.5 MB input; the other 6
//                    channels are only needed at match candidates).
//   Block NB       : 384-item match correction at candidate pixels (pixels
//                    listed in target_boxes; dedup by (r,c); first-match scan;
//                    rintf == jnp.round half-to-even). Runs CONCURRENTLY with
//                    the sum blocks.
//   Last block     : (threadfence-reduction pattern) folds 1025 partials in
//                    double, writes sum/denom. Deterministic regardless of
//                    which block arrives last.

#define NB 1024
#define NT 256
// conf planes: 24 total (b=0..7, a=0..2), each 65536 float4.
// 24*65536 = 1572864 = NB*NT*6 float4 loads.

__device__ __forceinline__ float sigmoidf_(float x) {
    // 1/(1+exp(-x)), exp via hardware v_exp_f32
    float e = __builtin_amdgcn_exp2f(-1.4426950408889634f * x);
    return 1.0f / (1.0f + e);
}

__global__ __launch_bounds__(NT) void fused_kernel(const float* __restrict__ pol,
                                                   const int* __restrict__ tb,
                                                   const float* __restrict__ tp,
                                                   float* __restrict__ partials,
                                                   unsigned int* __restrict__ counter,
                                                   float* __restrict__ out) {
    const int tid = threadIdx.x;
    const int blk = blockIdx.x;
    __shared__ float sw[NT / 64];

    if (blk < NB) {
        // ---- conf-sum slice ----
        const int gid = blk * NT + tid;
        const float4* p4 = (const float4*)pol;
        const int off = gid & 65535;   // constant across iterations
        const int p0 = gid >> 16;      // plane advances by 4 per iteration
        float acc = 0.f;
#pragma unroll
        for (int it = 0; it < 6; ++it) {
            int plane = p0 + 4 * it;               // 0..23 = b*3+a
            // conf channel index = b*9+a*3+2 = 3*plane+2  (no int div needed)
            float4 v = p4[((size_t)(3 * plane + 2) << 16) + off];
            float s0 = sigmoidf_(v.x), s1 = sigmoidf_(v.y);
            float s2 = sigmoidf_(v.z), s3 = sigmoidf_(v.w);
            acc += s0 * s0 + s1 * s1 + s2 * s2 + s3 * s3;
        }
#pragma unroll
        for (int o = 32; o; o >>= 1) acc += __shfl_down(acc, o);
        if ((tid & 63) == 0) sw[tid >> 6] = acc;
        __syncthreads();
        if (tid == 0) partials[blk] = sw[0] + sw[1] + sw[2] + sw[3];
    } else {
        // ---- match correction: item = (b*16 + t)*3 + a, 384 items ----
        float acc = 0.f;
        for (int it = tid; it < 384; it += NT) {
            int a = it % 3;
            int bt = it / 3;
            int t = bt & 15;
            int b = bt >> 4;
            const int* tbb = tb + b * 64;   // 16 boxes * 4
            int r = tbb[t * 4 + 0];
            int c = tbb[t * 4 + 1];
            // dedup: pixel already handled at an earlier t with same (r,c).
            // Valid because the fidx scan below covers ALL 16 boxes.
            bool dup = false;
            for (int t2 = 0; t2 < t; ++t2)
                if (tbb[t2 * 4 + 0] == r && tbb[t2 * 4 + 1] == c) { dup = true; break; }
            if (dup) continue;

            size_t base = ((size_t)(b * 9 + a * 3)) << 18;  // plane = 2^18 floats
            size_t pix = ((size_t)r << 9) + (size_t)c;
            float x0 = pol[base + pix];                 // delta_r logit
            float x1 = pol[base + (1 << 18) + pix];     // delta_c logit
            float x2 = pol[base + (2 << 18) + pix];     // conf logit
            float dr = sigmoidf_(x0) * 9.0f;
            float dc = sigmoidf_(x1) * 16.0f;
            float conf = sigmoidf_(x2);
            float pr2 = fminf((float)r + dr, 511.0f);   // low clip redundant
            float pc2 = fminf((float)c + dc, 511.0f);
            int pr2i = (int)rintf(pr2);                 // half-to-even == jnp.round
            int pc2i = (int)rintf(pc2);

            int fidx = -1;
            for (int t2 = 0; t2 < 16; ++t2) {
                if (tbb[t2 * 4 + 0] == r && tbb[t2 * 4 + 1] == c &&
                    tbb[t2 * 4 + 2] == pr2i && tbb[t2 * 4 + 3] == pc2i) { fidx = t2; break; }
            }
            if (fidx >= 0) {
                float tr2 = (float)tbb[fidx * 4 + 2];
                float tc2 = (float)tbb[fidx * 4 + 3];
                float tpv = tp[b * 16 + fidx];
                float coord = fabsf(pr2 - tr2) + fabsf(pc2 - tc2);
                float closs = (conf - tpv) * (conf - tpv);
                // subtract the fp_loss the sum blocks counted for this anchor
                acc += coord + closs - conf * conf;
            }
        }
#pragma unroll
        for (int o = 32; o; o >>= 1) acc += __shfl_down(acc, o);
        if ((tid & 63) == 0) sw[tid >> 6] = acc;
        __syncthreads();
        if (tid == 0) partials[NB] = sw[0] + sw[1] + sw[2] + sw[3];
    }

    // ---- completion detection (threadfence reduction) ----
    __shared__ unsigned last;
    if (tid == 0) {
        __threadfence();                         // make partial visible device-wide
        last = (atomicAdd(counter, 1u) == NB);   // old==NB -> I'm arrival NB+1 of NB+1
    }
    __syncthreads();
    if (last) {
        __threadfence();                         // acquire side
        double acc = 0.0;
        for (int j = tid; j <= NB; j += NT) acc += (double)partials[j];
#pragma unroll
        for (int o = 32; o; o >>= 1) acc += __shfl_down(acc, o);
        __shared__ double sd[NT / 64];
        if ((tid & 63) == 0) sd[tid >> 6] = acc;
        __syncthreads();
        if (tid == 0)
            out[0] = (float)((sd[0] + sd[1] + sd[2] + sd[3]) / 6291456.0); // /(8*512*512*3)
    }
}

extern "C" void kernel_launch(void* const* d_in, const int* in_sizes, int n_in,
                              void* d_out, int out_size, void* d_ws, size_t ws_size,
                              hipStream_t stream) {
    const float* pol = (const float*)d_in[0];   // (8,9,512,512) f32
    const int* tb = (const int*)d_in[1];        // (8,16,4) i32
    const float* tp = (const float*)d_in[2];    // (8,16) f32
    float* partials = (float*)d_ws;             // NB+1 floats
    unsigned int* counter = (unsigned int*)((char*)d_ws + 8192);
    float* out = (float*)d_out;

    hipMemsetAsync(counter, 0, 4, stream);      // counter starts poisoned 0xAA
    fused_kernel<<<NB + 1, NT, 0, stream>>>(pol, tb, tp, partials, counter, out);
}

// Round 4
// 118.305 us; speedup vs baseline: 1.1833x; 1.1833x over previous
//
#include <hip/hip_runtime.h>

// BoxDetectionLoss on MI355X — A/B round.
//  Kernel A  (NB+1 blocks): blocks 0..NB-1 sum sigmoid(conf)^2 (25.2 MB of the
//            75.5 MB input); block NB does the 384-item match correction.
//            NO fences / atomics (round-3's 49us stall suspect).
//  Kernel A2 (NB blocks): same sums, 6 float4 loads explicitly hoisted (MLP
//            test). Writes to partials2 (unused by B) — diagnostic only.
//  Kernel B  (1 block): double-precision fold of partials[0..NB] -> out.

#define NB 1024
#define NT 256
// conf planes: 24 (b=0..7, a=0..2), each 65536 float4. 24*65536 = NB*NT*6.

__device__ __forceinline__ float sigmoidf_(float x) {
    float e = __builtin_amdgcn_exp2f(-1.4426950408889634f * x);
    return 1.0f / (1.0f + e);
}

__global__ __launch_bounds__(NT) void sum_corr_kernel(const float* __restrict__ pol,
                                                      const int* __restrict__ tb,
                                                      const float* __restrict__ tp,
                                                      float* __restrict__ partials) {
    const int tid = threadIdx.x;
    const int blk = blockIdx.x;
    __shared__ float sw[NT / 64];
    float acc = 0.f;

    if (blk < NB) {
        // ---- conf-sum slice (identical structure to round 3) ----
        const int gid = blk * NT + tid;
        const float4* p4 = (const float4*)pol;
        const int off = gid & 65535;
        const int p0 = gid >> 16;
#pragma unroll
        for (int it = 0; it < 6; ++it) {
            int plane = p0 + 4 * it;               // 0..23 = b*3+a
            float4 v = p4[((size_t)(3 * plane + 2) << 16) + off]; // chan 3*plane+2
            float s0 = sigmoidf_(v.x), s1 = sigmoidf_(v.y);
            float s2 = sigmoidf_(v.z), s3 = sigmoidf_(v.w);
            acc += s0 * s0 + s1 * s1 + s2 * s2 + s3 * s3;
        }
    } else {
        // ---- match correction: item = (b*16 + t)*3 + a, 384 items ----
        for (int it = tid; it < 384; it += NT) {
            int a = it % 3;
            int bt = it / 3;
            int t = bt & 15;
            int b = bt >> 4;
            const int* tbb = tb + b * 64;
            int r = tbb[t * 4 + 0];
            int c = tbb[t * 4 + 1];
            bool dup = false;   // pixel already handled at earlier t
            for (int t2 = 0; t2 < t; ++t2)
                if (tbb[t2 * 4 + 0] == r && tbb[t2 * 4 + 1] == c) { dup = true; break; }
            if (dup) continue;

            size_t base = ((size_t)(b * 9 + a * 3)) << 18;
            size_t pix = ((size_t)r << 9) + (size_t)c;
            float x0 = pol[base + pix];
            float x1 = pol[base + (1 << 18) + pix];
            float x2 = pol[base + (2 << 18) + pix];
            float dr = sigmoidf_(x0) * 9.0f;
            float dc = sigmoidf_(x1) * 16.0f;
            float conf = sigmoidf_(x2);
            float pr2 = fminf((float)r + dr, 511.0f);
            float pc2 = fminf((float)c + dc, 511.0f);
            int pr2i = (int)rintf(pr2);            // half-to-even == jnp.round
            int pc2i = (int)rintf(pc2);

            int fidx = -1;
            for (int t2 = 0; t2 < 16; ++t2) {
                if (tbb[t2 * 4 + 0] == r && tbb[t2 * 4 + 1] == c &&
                    tbb[t2 * 4 + 2] == pr2i && tbb[t2 * 4 + 3] == pc2i) { fidx = t2; break; }
            }
            if (fidx >= 0) {
                float tr2 = (float)tbb[fidx * 4 + 2];
                float tc2 = (float)tbb[fidx * 4 + 3];
                float tpv = tp[b * 16 + fidx];
                float coord = fabsf(pr2 - tr2) + fabsf(pc2 - tc2);
                float closs = (conf - tpv) * (conf - tpv);
                acc += coord + closs - conf * conf;  // replace fp_loss for match
            }
        }
    }

#pragma unroll
    for (int o = 32; o; o >>= 1) acc += __shfl_down(acc, o);
    if ((tid & 63) == 0) sw[tid >> 6] = acc;
    __syncthreads();
    if (tid == 0) partials[blk] = sw[0] + sw[1] + sw[2] + sw[3];
}

// Diagnostic variant: all 6 loads issued before any compute (MLP x6).
__global__ __launch_bounds__(NT) void sum_hoist_kernel(const float* __restrict__ pol,
                                                       float* __restrict__ partials2) {
    const int tid = threadIdx.x;
    const int gid = blockIdx.x * NT + tid;
    const float4* p4 = (const float4*)pol;
    const int off = gid & 65535;
    const int p0 = gid >> 16;
    float4 v[6];
#pragma unroll
    for (int it = 0; it < 6; ++it)
        v[it] = p4[((size_t)(3 * (p0 + 4 * it) + 2) << 16) + off];
    float acc = 0.f;
#pragma unroll
    for (int it = 0; it < 6; ++it) {
        float s0 = sigmoidf_(v[it].x), s1 = sigmoidf_(v[it].y);
        float s2 = sigmoidf_(v[it].z), s3 = sigmoidf_(v[it].w);
        acc += s0 * s0 + s1 * s1 + s2 * s2 + s3 * s3;
    }
#pragma unroll
    for (int o = 32; o; o >>= 1) acc += __shfl_down(acc, o);
    __shared__ float sw[NT / 64];
    if ((tid & 63) == 0) sw[tid >> 6] = acc;
    __syncthreads();
    if (tid == 0) partials2[blockIdx.x] = sw[0] + sw[1] + sw[2] + sw[3];
}

__global__ __launch_bounds__(NT) void fold_kernel(const float* __restrict__ partials,
                                                  float* __restrict__ out) {
    const int tid = threadIdx.x;
    double acc = 0.0;
    for (int j = tid; j <= NB; j += NT) acc += (double)partials[j];
#pragma unroll
    for (int o = 32; o; o >>= 1) acc += __shfl_down(acc, o);
    __shared__ double sd[NT / 64];
    if ((tid & 63) == 0) sd[tid >> 6] = acc;
    __syncthreads();
    if (tid == 0)
        out[0] = (float)((sd[0] + sd[1] + sd[2] + sd[3]) / 6291456.0); // 8*512*512*3
}

extern "C" void kernel_launch(void* const* d_in, const int* in_sizes, int n_in,
                              void* d_out, int out_size, void* d_ws, size_t ws_size,
                              hipStream_t stream) {
    const float* pol = (const float*)d_in[0];   // (8,9,512,512) f32
    const int* tb = (const int*)d_in[1];        // (8,16,4) i32
    const float* tp = (const float*)d_in[2];    // (8,16) f32
    float* partials = (float*)d_ws;             // NB+1 floats
    float* partials2 = (float*)((char*)d_ws + 8192);  // NB floats (diagnostic)
    float* out = (float*)d_out;

    sum_corr_kernel<<<NB + 1, NT, 0, stream>>>(pol, tb, tp, partials);
    sum_hoist_kernel<<<NB, NT, 0, stream>>>(pol, partials2);
    fold_kernel<<<1, NT, 0, stream>>>(partials, out);
}

// Round 5
// 112.412 us; speedup vs baseline: 1.2453x; 1.0524x over previous
//
#include <hip/hip_runtime.h>

// BoxDetectionLoss on MI355X — final minimal structure.
//  Kernel 1 (NB+1 blocks): blocks 0..NB-1 sum sigmoid(conf)^2 over the 3 conf
//            channels per batch (25.2 MB of 75.5 MB input — the info floor:
//            fp_loss needs every conf logit; delta channels only matter at
//            match candidates). Block NB computes the 384-item match
//            correction CONCURRENTLY (pixels listed in target_boxes; dedup by
//            (r,c); first-match scan; rintf == jnp.round half-to-even).
//            NO device-scope fences/atomics (round-3 A/B: 1025x threadfence
//            + atomic cost ~45 us flat).
//  Kernel 2 (1 block): double-precision fold of partials[0..NB] -> sum/denom.
//            Inter-kernel visibility via stream order (end-of-kernel release).

#define NB 1024
#define NT 256
// conf planes: 24 (b=0..7, a=0..2), each 65536 float4. 24*65536 = NB*NT*6.

__device__ __forceinline__ float sigmoidf_(float x) {
    float e = __builtin_amdgcn_exp2f(-1.4426950408889634f * x);
    return 1.0f / (1.0f + e);
}

__global__ __launch_bounds__(NT) void sum_corr_kernel(const float* __restrict__ pol,
                                                      const int* __restrict__ tb,
                                                      const float* __restrict__ tp,
                                                      float* __restrict__ partials) {
    const int tid = threadIdx.x;
    const int blk = blockIdx.x;
    __shared__ float sw[NT / 64];
    float acc = 0.f;

    if (blk < NB) {
        // ---- conf-sum slice: 6 float4 per lane, L3-resident on replays ----
        const int gid = blk * NT + tid;
        const float4* p4 = (const float4*)pol;
        const int off = gid & 65535;
        const int p0 = gid >> 16;
#pragma unroll
        for (int it = 0; it < 6; ++it) {
            int plane = p0 + 4 * it;               // 0..23 = b*3+a
            float4 v = p4[((size_t)(3 * plane + 2) << 16) + off]; // chan 3*plane+2
            float s0 = sigmoidf_(v.x), s1 = sigmoidf_(v.y);
            float s2 = sigmoidf_(v.z), s3 = sigmoidf_(v.w);
            acc += s0 * s0 + s1 * s1 + s2 * s2 + s3 * s3;
        }
    } else {
        // ---- match correction: item = (b*16 + t)*3 + a, 384 items ----
        for (int it = tid; it < 384; it += NT) {
            int a = it % 3;
            int bt = it / 3;
            int t = bt & 15;
            int b = bt >> 4;
            const int* tbb = tb + b * 64;
            int r = tbb[t * 4 + 0];
            int c = tbb[t * 4 + 1];
            bool dup = false;   // pixel handled at an earlier t with same (r,c)
            for (int t2 = 0; t2 < t; ++t2)
                if (tbb[t2 * 4 + 0] == r && tbb[t2 * 4 + 1] == c) { dup = true; break; }
            if (dup) continue;

            size_t base = ((size_t)(b * 9 + a * 3)) << 18;  // plane = 2^18 floats
            size_t pix = ((size_t)r << 9) + (size_t)c;
            float x0 = pol[base + pix];                 // delta_r logit
            float x1 = pol[base + (1 << 18) + pix];     // delta_c logit
            float x2 = pol[base + (2 << 18) + pix];     // conf logit
            float dr = sigmoidf_(x0) * 9.0f;
            float dc = sigmoidf_(x1) * 16.0f;
            float conf = sigmoidf_(x2);
            float pr2 = fminf((float)r + dr, 511.0f);   // low clip redundant
            float pc2 = fminf((float)c + dc, 511.0f);
            int pr2i = (int)rintf(pr2);                 // half-to-even == jnp.round
            int pc2i = (int)rintf(pc2);

            int fidx = -1;                              // first-match scan, all 16
            for (int t2 = 0; t2 < 16; ++t2) {
                if (tbb[t2 * 4 + 0] == r && tbb[t2 * 4 + 1] == c &&
                    tbb[t2 * 4 + 2] == pr2i && tbb[t2 * 4 + 3] == pc2i) { fidx = t2; break; }
            }
            if (fidx >= 0) {
                float tr2 = (float)tbb[fidx * 4 + 2];
                float tc2 = (float)tbb[fidx * 4 + 3];
                float tpv = tp[b * 16 + fidx];
                float coord = fabsf(pr2 - tr2) + fabsf(pc2 - tc2);
                float closs = (conf - tpv) * (conf - tpv);
                acc += coord + closs - conf * conf;  // swap fp_loss -> match loss
            }
        }
    }

#pragma unroll
    for (int o = 32; o; o >>= 1) acc += __shfl_down(acc, o);
    if ((tid & 63) == 0) sw[tid >> 6] = acc;
    __syncthreads();
    if (tid == 0) partials[blk] = sw[0] + sw[1] + sw[2] + sw[3];
}

__global__ __launch_bounds__(NT) void fold_kernel(const float* __restrict__ partials,
                                                  float* __restrict__ out) {
    const int tid = threadIdx.x;
    double acc = 0.0;
    for (int j = tid; j <= NB; j += NT) acc += (double)partials[j];
#pragma unroll
    for (int o = 32; o; o >>= 1) acc += __shfl_down(acc, o);
    __shared__ double sd[NT / 64];
    if ((tid & 63) == 0) sd[tid >> 6] = acc;
    __syncthreads();
    if (tid == 0)
        out[0] = (float)((sd[0] + sd[1] + sd[2] + sd[3]) / 6291456.0); // 8*512*512*3
}

extern "C" void kernel_launch(void* const* d_in, const int* in_sizes, int n_in,
                              void* d_out, int out_size, void* d_ws, size_t ws_size,
                              hipStream_t stream) {
    const float* pol = (const float*)d_in[0];   // (8,9,512,512) f32
    const int* tb = (const int*)d_in[1];        // (8,16,4) i32
    const float* tp = (const float*)d_in[2];    // (8,16) f32
    float* partials = (float*)d_ws;             // NB+1 floats
    float* out = (float*)d_out;

    sum_corr_kernel<<<NB + 1, NT, 0, stream>>>(pol, tb, tp, partials);
    fold_kernel<<<1, NT, 0, stream>>>(partials, out);
}